// Round 18
// baseline (419.464 us; speedup 1.0000x reference)
//
#include <hip/hip_runtime.h>

typedef unsigned short u16;
typedef unsigned int u32;
typedef __attribute__((ext_vector_type(8))) __bf16 bf16x8;
typedef __attribute__((ext_vector_type(4))) float f32x4;

#define E_TILE 128
#define KL 136       // h LDS row stride in u16 (272 B rows)
#define CBS 136      // bf16 coef stride in u16
#define WNTOT 2304
#define NTILES 144   // 2304 / 16
#define TPS 132      // tp stride in f32
#define UREG 21120   // u16 units: max(h 17408, coefb 17408, tp 21120)

#define A0C   0.14433756729740643f   /* sqrt(1/48) */
#define A0IS3 0.08333333333333333f   /* A0/sqrt(3) = 1/12 */
#define A1IS3 0.14433756729740643f   /* (1/4)/sqrt(3) */

__device__ inline u16 f2bf(float f) {
    union { float f; u32 u; } v; v.f = f;
    u32 u = v.u;
    return (u16)((u + 0x7FFFu + ((u >> 16) & 1u)) >> 16);  // RNE
}
__device__ inline float bf2f(u16 s) {
    union { u32 u; float f; } v; v.u = ((u32)s) << 16; return v.f;
}

// w2frag: fragment-ordered W2T, K=128 (idx = ((nt*4+kk)*64+lane)*8+j;
//   n = nt*16+(lane&15); k = kk*32+(lane>>4)*8+j; value = W2[k][n])
// w1t[n][k] = W1[k][n].  Also fused: per-edge src count (grid covers E).
__global__ void prep_w(const float* __restrict__ w2, const float* __restrict__ w1,
                       u16* __restrict__ w2frag, u16* __restrict__ w1t,
                       const int* __restrict__ ei, int E, int* __restrict__ cnt) {
    int idx = blockIdx.x * 256 + threadIdx.x;
    if (idx < E) atomicAdd(&cnt[ei[idx]], 1);   // fused count_k
    const int tot2 = NTILES * 4 * 64 * 8;   // 294912
    if (idx < tot2) {
        int j = idx & 7;
        int l = (idx >> 3) & 63;
        int f = idx >> 9;
        int nt = f >> 2, kk = f & 3;
        int n = nt * 16 + (l & 15);
        int k = kk * 32 + (l >> 4) * 8 + j;
        w2frag[idx] = f2bf(w2[(size_t)k * WNTOT + n]);
    } else {
        int j = idx - tot2;
        if (j < 128 * 32) {
            int n = j >> 5, k = j & 31;
            w1t[j] = f2bf(w1[k * 128 + n]);
        }
    }
}

// single block, 1024 threads: cur = exclusive-prefix-sum(cnt); rcn = 1/max(cnt,1)
__global__ void scan_k(const int* __restrict__ cnt, int* __restrict__ cur,
                       float* __restrict__ rcn, int N) {
    __shared__ int part[1024];
    int t = threadIdx.x;
    int S = (N + 1023) >> 10;
    int lo = t * S; if (lo > N) lo = N;
    int hi = lo + S; if (hi > N) hi = N;
    int s = 0;
    for (int i = lo; i < hi; ++i) s += cnt[i];
    part[t] = s;
    __syncthreads();
    for (int d = 1; d < 1024; d <<= 1) {
        int add = (t >= d) ? part[t - d] : 0;
        __syncthreads();
        part[t] += add;
        __syncthreads();
    }
    int run = part[t] - s;   // exclusive
    for (int i = lo; i < hi; ++i) {
        int c = cnt[i];
        cur[i] = run;
        run += c;
        rcn[i] = 1.0f / fmaxf((float)c, 1.0f);
    }
}

__global__ void scatter_k(const int* __restrict__ ei, int E,
                          int* __restrict__ cur, int* __restrict__ perm) {
    int e = blockIdx.x * 256 + threadIdx.x;
    if (e < E) {
        int s = ei[e];
        int p = atomicAdd(&cur[s], 1);
        perm[p] = e;
    }
}

__global__ __launch_bounds__(256, 3)   // 170-reg budget; live ~140 (2 edge-groups) — r13 optimum
void tpcl_main(const float* __restrict__ node_attr,
               const int* __restrict__ edge_index,
               const float* __restrict__ edge_attr,
               const float* __restrict__ edge_sh,
               const u16* __restrict__ w1t,
               const float* __restrict__ fc_b1,
               const float* __restrict__ fc_b2,
               const u16* __restrict__ w2frag,
               const int* __restrict__ perm,
               const float* __restrict__ rcn,
               float* __restrict__ out,
               int N, int E)
{
    // Phase-unioned region (42240 B):
    //   phase 1 : h [128][KL] u16 (34816 B)
    //   phase 1b/2: coefb bf16 [128][CBS] (34816 B)  rows: 0..31 L1, 32..63 X0, 64..111 X1, 112..127 L4
    //   phase 3 : tp f32 [80][TPS] (42240 B)
    alignas(16) __shared__ u16 uregion[UREG];
    __shared__ float SHs[E_TILE][4];   // RAW sh0, s1a, s1b, s1c
    __shared__ int SRCs[E_TILE];
    __shared__ int RLEN[E_TILE];

    const int tid = threadIdx.x;
    const int ebase = blockIdx.x * E_TILE;
    const int lane = tid & 63;
    const int wave = tid >> 6;

    // ---- Phase 0b: edge_index/edge_sh -> SRCs, SHs(raw); 2 threads/edge ----
    const int ce = tid >> 1, t2 = tid & 1;
    bool cvalid;
    int cdst;
    {
        int eg = ebase + ce;
        int pe = (eg < E) ? perm[eg] : -1;
        cvalid = pe >= 0;
        cdst = 0;
        if (t2 == 0) {
            int srci = -1;
            float sh0 = 0.f, s1a = 0.f, s1b = 0.f, s1c = 0.f;
            if (cvalid) {
                srci = edge_index[pe];
                sh0  = edge_sh[(size_t)pe * 4 + 0];
                s1a  = edge_sh[(size_t)pe * 4 + 1];
                s1b  = edge_sh[(size_t)pe * 4 + 2];
                s1c  = edge_sh[(size_t)pe * 4 + 3];
            }
            SRCs[ce] = srci;
            SHs[ce][0] = sh0;
            SHs[ce][1] = s1a;
            SHs[ce][2] = s1b;
            SHs[ce][3] = s1c;
        }
        if (cvalid) cdst = edge_index[E + pe];
    }
    __syncthreads();

    // ---- run lengths in sorted-src tile ----
    if (tid < E_TILE) {
        int e = tid;
        int s = SRCs[e];
        bool start = (e == 0) || (SRCs[e - 1] != s);
        int len = 0;
        if (start) {
            int end = e + 1;
            while (end < E_TILE && SRCs[end] == s) ++end;
            len = end - e;
        }
        RLEN[e] = len;
    }

    // ---- Phase 1: h = relu(ea @ W1 + b1) via MFMA; ea direct global->reg ----
    u16 (*h_lds)[KL] = (u16(*)[KL])uregion;
    {
        const int e16p = lane & 15;
        const int ko1 = (lane >> 4) * 8;
#pragma unroll
        for (int m = 0; m < 2; ++m) {
            int erow = (wave * 2 + m) * 16 + e16p;
            int eg = ebase + erow;
            bool v = eg < E;
            int pe = v ? perm[eg] : 0;
            f32x4 f0 = {0.f, 0.f, 0.f, 0.f}, f1 = {0.f, 0.f, 0.f, 0.f};
            if (v) {
                const float* eap = edge_attr + (size_t)pe * 32 + ko1;
                f0 = *(const f32x4*)(eap);
                f1 = *(const f32x4*)(eap + 4);
            }
            bf16x8 eafr;
            u16* ep = (u16*)&eafr;
#pragma unroll
            for (int j = 0; j < 4; ++j) {
                ep[j]     = f2bf(f0[j]);
                ep[4 + j] = f2bf(f1[j]);
            }
            int r0 = (wave * 2 + m) * 16 + (lane >> 4) * 4;
#pragma unroll
            for (int nt = 0; nt < 8; ++nt) {
                int ncol = nt * 16 + e16p;
                bf16x8 bfr = *(const bf16x8*)&w1t[(size_t)ncol * 32 + ko1];
                f32x4 acc = {0.f, 0.f, 0.f, 0.f};
                acc = __builtin_amdgcn_mfma_f32_16x16x32_bf16(eafr, bfr, acc, 0, 0, 0);
                float b = fc_b1[ncol];
#pragma unroll
                for (int r = 0; r < 4; ++r)
                    h_lds[r0 + r][ncol] = f2bf(fmaxf(acc[r] + b, 0.f));
            }
        }
    }
    __syncthreads();

    // ---- B fragments: wave owns TWO 16-edge groups (AI x2 on the W2 stream) ----
    const int e16 = lane & 15;
    const int hi  = lane >> 4;
    const int elA = wave * 16 + e16;
    const int elB = 64 + elA;
    const int ko  = hi * 8;
    bf16x8 hfA[4], hfB[4];
#pragma unroll
    for (int kk = 0; kk < 4; ++kk) {
        hfA[kk] = *(const bf16x8*)&h_lds[elA][kk * 32 + ko];
        hfB[kk] = *(const bf16x8*)&h_lds[elB][kk * 32 + ko];
    }
    __syncthreads();   // h dead -> coefb overlay may be written

    // ---- Phase 1b: gather node_attr[dst], build bf16 coef tables (overlay) ----
    u16* coefb = uregion;
    {
        float sh0 = SHs[ce][0], s1a = SHs[ce][1], s1b = SHs[ce][2], s1c = SHs[ce][3];
        const float* na = node_attr + (size_t)cdst * 80;
        float l1c = A0C * sh0;
#pragma unroll
        for (int q = 0; q < 16; ++q) {
            int u = q * 2 + t2;
            float x = cvalid ? na[u] : 0.f;
            coefb[u * CBS + ce]        = f2bf(l1c * x);
            coefb[(32 + u) * CBS + ce] = f2bf(x);
        }
#pragma unroll
        for (int q = 0; q < 8; ++q) {
            int u = q * 2 + t2;
            float xa = cvalid ? na[32 + u * 3 + 0] : 0.f;
            float xb = cvalid ? na[32 + u * 3 + 1] : 0.f;
            float xc = cvalid ? na[32 + u * 3 + 2] : 0.f;
            coefb[(64 + u * 3 + 0) * CBS + ce] = f2bf(xa);
            coefb[(64 + u * 3 + 1) * CBS + ce] = f2bf(xb);
            coefb[(64 + u * 3 + 2) * CBS + ce] = f2bf(xc);
            coefb[(112 + u) * CBS + ce] = f2bf(A0IS3 * (xa * s1a + xb * s1b + xc * s1c));
        }
    }
    __syncthreads();

    // Per-group accumulators: lane owns edges elA/elB, n-rows 4*hi+r of each tile.
    float o0aA[4] = {}, o0bA[4] = {}, q2A[4] = {}, q3A[3][4] = {};
    float o0aB[4] = {}, o0bB[4] = {}, q2B[4] = {}, q3B[3][4] = {};

    auto epi = [&](const f32x4& acc, const f32x4& bv, int gnt, int el,
                   float (&o0a)[4], float (&o0b)[4], float (&q2)[4], float (&q3)[3][4]) {
        float av[4];
#pragma unroll
        for (int r = 0; r < 4; ++r) av[r] = acc[r] + bv[r];
        if (gnt < 64) {
            float c = bf2f(coefb[(gnt >> 1) * CBS + el]);
            if (gnt & 1) {
#pragma unroll
                for (int r = 0; r < 4; ++r) o0b[r] += c * av[r];
            } else {
#pragma unroll
                for (int r = 0; r < 4; ++r) o0a[r] += c * av[r];
            }
        } else if (gnt < 96) {
            float c = bf2f(coefb[(32 + gnt - 64) * CBS + el]);
#pragma unroll
            for (int r = 0; r < 4; ++r) q2[r] += c * av[r];
        } else if (gnt < 112) {
            int u = gnt - 96;
            float c0 = bf2f(coefb[(64 + u * 3 + 0) * CBS + el]);
            float c1 = bf2f(coefb[(64 + u * 3 + 1) * CBS + el]);
            float c2 = bf2f(coefb[(64 + u * 3 + 2) * CBS + el]);
#pragma unroll
            for (int r = 0; r < 4; ++r) {
                float a = av[r];
                q3[0][r] += c0 * a;
                q3[1][r] += c1 * a;
                q3[2][r] += c2 * a;
            }
        } else {
            int idx = gnt - 112;
            float c = bf2f(coefb[(112 + (idx >> 1)) * CBS + el]);
            if (idx & 1) {
#pragma unroll
                for (int r = 0; r < 4; ++r) o0b[r] += c * av[r];
            } else {
#pragma unroll
                for (int r = 0; r < 4; ++r) o0a[r] += c * av[r];
            }
        }
    };

    auto step = [&](const bf16x8 (&afr)[4], const f32x4& bv, int gnt) {
        f32x4 accA = {0.f, 0.f, 0.f, 0.f};
        f32x4 accB = {0.f, 0.f, 0.f, 0.f};
#pragma unroll
        for (int kk = 0; kk < 4; ++kk) {   // one A-load feeds BOTH edge groups
            accA = __builtin_amdgcn_mfma_f32_16x16x32_bf16(afr[kk], hfA[kk], accA, 0, 0, 0);
            accB = __builtin_amdgcn_mfma_f32_16x16x32_bf16(afr[kk], hfB[kk], accB, 0, 0, 0);
        }
        epi(accA, bv, gnt, elA, o0aA, o0bA, q2A, q3A);
        epi(accB, bv, gnt, elB, o0aB, o0bB, q2B, q3B);
    };

    // ---- Phase 2: 144 N-tiles; A = W2 stream from L2, 2-deep reg prefetch ----
    const u16* pt = w2frag + (size_t)lane * 8;   // tile stride 2048 u16
    const float* b2p = fc_b2 + hi * 4;           // + 16 per tile
    bf16x8 aA[4], aB[4];
    f32x4 bvA, bvB;
#pragma unroll
    for (int kk = 0; kk < 4; ++kk) aA[kk] = *(const bf16x8*)(pt + kk * 512);
    bvA = *(const f32x4*)(b2p + 0);
    for (int t = 0; t < 144; t += 2) {
#pragma unroll
        for (int kk = 0; kk < 4; ++kk) aB[kk] = *(const bf16x8*)(pt + 2048 + kk * 512);
        bvB = *(const f32x4*)(b2p + (t + 1) * 16);
        step(aA, bvA, t);
        if (t + 2 < 144) {
#pragma unroll
            for (int kk = 0; kk < 4; ++kk) aA[kk] = *(const bf16x8*)(pt + 4096 + kk * 512);
            bvA = *(const f32x4*)(b2p + (t + 2) * 16);
        }
        step(aB, bvB, t + 1);
        pt += 4096;
    }
    __syncthreads();   // coefb dead -> tp overlay may be written

    // ---- Phase 3a: write per-edge outputs for both groups ----
    float* tp = (float*)uregion;
    {
        auto wout = [&](int el, float (&o0a)[4], float (&o0b)[4],
                        float (&q2)[4], float (&q3)[3][4]) {
            float sh0 = SHs[el][0], s1a = SHs[el][1], s1b = SHs[el][2], s1c = SHs[el][3];
            float g  = A1IS3 * sh0;
            float sa = A1IS3 * s1a, sb = A1IS3 * s1b, sc = A1IS3 * s1c;
#pragma unroll
            for (int r = 0; r < 4; ++r) {
                int v = hi * 4 + r;
                tp[v * TPS + el]        = o0a[r];
                tp[(16 + v) * TPS + el] = o0b[r];
                float qv = q2[r];
                tp[(32 + 3 * v + 0) * TPS + el] = qv * sa + g * q3[0][r];
                tp[(32 + 3 * v + 1) * TPS + el] = qv * sb + g * q3[1][r];
                tp[(32 + 3 * v + 2) * TPS + el] = qv * sc + g * q3[2][r];
            }
        };
        wout(elA, o0aA, o0bA, q2A, q3A);
        wout(elB, o0aB, o0bB, q2B, q3B);
    }
    __syncthreads();

    // ---- Phase 3b: per-run serial sum, scaled by 1/cnt (replaces finalize_k),
    //      one atomic per (run, component) ----
    for (int i = tid; i < E_TILE * 80; i += 256) {
        int e = i & 127, c = i >> 7;
        int len = RLEN[e];
        if (len > 0 && SRCs[e] >= 0) {
            float s = 0.f;
            for (int k = 0; k < len; ++k) s += tp[c * TPS + e + k];
            int src = SRCs[e];
            unsafeAtomicAdd(&out[(size_t)src * 80 + c], s * rcn[src]);
        }
    }
}

extern "C" void kernel_launch(void* const* d_in, const int* in_sizes, int n_in,
                              void* d_out, int out_size, void* d_ws, size_t ws_size,
                              hipStream_t stream) {
    const float* node_attr  = (const float*)d_in[0];
    const int*   edge_index = (const int*)d_in[1];
    const float* edge_attr  = (const float*)d_in[2];
    const float* edge_sh    = (const float*)d_in[3];
    const float* fc_w1      = (const float*)d_in[4];
    const float* fc_b1      = (const float*)d_in[5];
    const float* fc_w2      = (const float*)d_in[6];
    const float* fc_b2      = (const float*)d_in[7];
    int N = in_sizes[0] / 80;
    int E = in_sizes[1] / 2;
    float* out = (float*)d_out;

    int*   cnt  = (int*)d_ws;
    int*   cur  = cnt + N;
    float* rcn  = (float*)(cur + N);
    int*   perm = (int*)(rcn + N);
    u16*   w2frag = (u16*)(perm + E);            // 294912 u16
    u16*   w1t    = w2frag + (size_t)NTILES * 4 * 64 * 8;

    hipMemsetAsync(out, 0, (size_t)N * 80 * 4, stream);
    hipMemsetAsync(cnt, 0, (size_t)N * 4, stream);

    int prep_total = NTILES * 4 * 64 * 8 + 128 * 32;
    prep_w<<<(prep_total + 255) / 256, 256, 0, stream>>>(
        fc_w2, fc_w1, w2frag, w1t, edge_index, E, cnt);
    scan_k<<<1, 1024, 0, stream>>>(cnt, cur, rcn, N);
    scatter_k<<<(E + 255) / 256, 256, 0, stream>>>(edge_index, E, cur, perm);
    tpcl_main<<<(E + E_TILE - 1) / E_TILE, 256, 0, stream>>>(
        node_attr, edge_index, edge_attr, edge_sh, w1t, fc_b1, fc_b2, w2frag, perm, rcn,
        out, N, E);
}

// Round 19
// 391.513 us; speedup vs baseline: 1.0714x; 1.0714x over previous
//
#include <hip/hip_runtime.h>

typedef unsigned short u16;
typedef unsigned int u32;
typedef __attribute__((ext_vector_type(8))) __bf16 bf16x8;
typedef __attribute__((ext_vector_type(4))) float f32x4;

#define E_TILE 128
#define KL 136       // h LDS row stride in u16 (272 B rows)
#define CBS 136      // bf16 coef stride in u16
#define WNTOT 2304
#define NTILES 144   // 2304 / 16
#define TPS 132      // tp stride in f32
#define UREG 21120   // u16 units: max(h 17408, coefb 17408, tp 21120)

#define A0C   0.14433756729740643f   /* sqrt(1/48) */
#define A0IS3 0.08333333333333333f   /* A0/sqrt(3) = 1/12 */
#define A1IS3 0.14433756729740643f   /* (1/4)/sqrt(3) */

__device__ inline u16 f2bf(float f) {
    union { float f; u32 u; } v; v.f = f;
    u32 u = v.u;
    return (u16)((u + 0x7FFFu + ((u >> 16) & 1u)) >> 16);  // RNE
}
__device__ inline float bf2f(u16 s) {
    union { u32 u; float f; } v; v.u = ((u32)s) << 16; return v.f;
}

// w2frag: fragment-ordered W2T, K=128.
//   idx = ((nt*4 + kk)*64 + lane)*8 + j
//   n = nt*16 + (lane&15); k = kk*32 + (lane>>4)*8 + j;  value = W2[k][n]
// w1t[n][k] = W1[k][n]
__global__ void prep_w(const float* __restrict__ w2, const float* __restrict__ w1,
                       u16* __restrict__ w2frag, u16* __restrict__ w1t) {
    int idx = blockIdx.x * 256 + threadIdx.x;
    const int tot2 = NTILES * 4 * 64 * 8;   // 294912
    if (idx < tot2) {
        int j = idx & 7;
        int l = (idx >> 3) & 63;
        int f = idx >> 9;
        int nt = f >> 2, kk = f & 3;
        int n = nt * 16 + (l & 15);
        int k = kk * 32 + (l >> 4) * 8 + j;
        w2frag[idx] = f2bf(w2[(size_t)k * WNTOT + n]);
    } else {
        int j = idx - tot2;
        if (j < 128 * 32) {
            int n = j >> 5, k = j & 31;
            w1t[j] = f2bf(w1[k * 128 + n]);
        }
    }
}

__global__ void count_k(const int* __restrict__ src, int E, int* __restrict__ cnt) {
    int i = blockIdx.x * 256 + threadIdx.x;
    if (i < E) atomicAdd(&cnt[src[i]], 1);
}

// single block, 1024 threads: cur = exclusive-prefix-sum(cnt)
__global__ void scan_k(const int* __restrict__ cnt, int* __restrict__ cur, int N) {
    __shared__ int part[1024];
    int t = threadIdx.x;
    int S = (N + 1023) >> 10;
    int lo = t * S; if (lo > N) lo = N;
    int hi = lo + S; if (hi > N) hi = N;
    int s = 0;
    for (int i = lo; i < hi; ++i) s += cnt[i];
    part[t] = s;
    __syncthreads();
    for (int d = 1; d < 1024; d <<= 1) {
        int add = (t >= d) ? part[t - d] : 0;
        __syncthreads();
        part[t] += add;
        __syncthreads();
    }
    int run = part[t] - s;   // exclusive
    for (int i = lo; i < hi; ++i) { cur[i] = run; run += cnt[i]; }
}

__global__ void scatter_k(const int* __restrict__ ei, int E,
                          int* __restrict__ cur, int* __restrict__ perm) {
    int e = blockIdx.x * 256 + threadIdx.x;
    if (e < E) {
        int s = ei[e];
        int p = atomicAdd(&cur[s], 1);
        perm[p] = e;
    }
}

__global__ void finalize_k(float* __restrict__ out, const int* __restrict__ cnt, int total) {
    int i = blockIdx.x * 256 + threadIdx.x;
    if (i >= total) return;
    float c = (float)cnt[i / 80];
    out[i] /= fmaxf(c, 1.0f);
}

__global__ __launch_bounds__(256, 3)   // 170-reg budget; live ~140 (2 edge-groups) — r13 optimum
void tpcl_main(const float* __restrict__ node_attr,
               const int* __restrict__ edge_index,
               const float* __restrict__ edge_attr,
               const float* __restrict__ edge_sh,
               const u16* __restrict__ w1t,
               const float* __restrict__ fc_b1,
               const float* __restrict__ fc_b2,
               const u16* __restrict__ w2frag,
               const int* __restrict__ perm,
               float* __restrict__ out,
               int N, int E)
{
    // Phase-unioned region (42240 B):
    //   phase 1 : h [128][KL] u16 (34816 B)
    //   phase 1b/2: coefb bf16 [128][CBS] (34816 B)  rows: 0..31 L1, 32..63 X0, 64..111 X1, 112..127 L4
    //   phase 3 : tp f32 [80][TPS] (42240 B)
    alignas(16) __shared__ u16 uregion[UREG];
    __shared__ float SHs[E_TILE][4];   // RAW sh0, s1a, s1b, s1c
    __shared__ int SRCs[E_TILE];
    __shared__ int RLEN[E_TILE];

    const int tid = threadIdx.x;
    const int ebase = blockIdx.x * E_TILE;
    const int lane = tid & 63;
    const int wave = tid >> 6;

    // ---- Phase 0b: edge_index/edge_sh -> SRCs, SHs(raw); 2 threads/edge ----
    const int ce = tid >> 1, t2 = tid & 1;
    bool cvalid;
    int cdst;
    {
        int eg = ebase + ce;
        int pe = (eg < E) ? perm[eg] : -1;
        cvalid = pe >= 0;
        cdst = 0;
        if (t2 == 0) {
            int srci = -1;
            float sh0 = 0.f, s1a = 0.f, s1b = 0.f, s1c = 0.f;
            if (cvalid) {
                srci = edge_index[pe];
                sh0  = edge_sh[(size_t)pe * 4 + 0];
                s1a  = edge_sh[(size_t)pe * 4 + 1];
                s1b  = edge_sh[(size_t)pe * 4 + 2];
                s1c  = edge_sh[(size_t)pe * 4 + 3];
            }
            SRCs[ce] = srci;
            SHs[ce][0] = sh0;
            SHs[ce][1] = s1a;
            SHs[ce][2] = s1b;
            SHs[ce][3] = s1c;
        }
        if (cvalid) cdst = edge_index[E + pe];
    }
    __syncthreads();

    // ---- run lengths in sorted-src tile ----
    if (tid < E_TILE) {
        int e = tid;
        int s = SRCs[e];
        bool start = (e == 0) || (SRCs[e - 1] != s);
        int len = 0;
        if (start) {
            int end = e + 1;
            while (end < E_TILE && SRCs[end] == s) ++end;
            len = end - e;
        }
        RLEN[e] = len;
    }

    // ---- Phase 1: h = relu(ea @ W1 + b1) via MFMA; ea direct global->reg ----
    u16 (*h_lds)[KL] = (u16(*)[KL])uregion;
    {
        const int e16p = lane & 15;
        const int ko1 = (lane >> 4) * 8;
#pragma unroll
        for (int m = 0; m < 2; ++m) {
            int erow = (wave * 2 + m) * 16 + e16p;
            int eg = ebase + erow;
            bool v = eg < E;
            int pe = v ? perm[eg] : 0;
            f32x4 f0 = {0.f, 0.f, 0.f, 0.f}, f1 = {0.f, 0.f, 0.f, 0.f};
            if (v) {
                const float* eap = edge_attr + (size_t)pe * 32 + ko1;
                f0 = *(const f32x4*)(eap);
                f1 = *(const f32x4*)(eap + 4);
            }
            bf16x8 eafr;
            u16* ep = (u16*)&eafr;
#pragma unroll
            for (int j = 0; j < 4; ++j) {
                ep[j]     = f2bf(f0[j]);
                ep[4 + j] = f2bf(f1[j]);
            }
            int r0 = (wave * 2 + m) * 16 + (lane >> 4) * 4;
#pragma unroll
            for (int nt = 0; nt < 8; ++nt) {
                int ncol = nt * 16 + e16p;
                bf16x8 bfr = *(const bf16x8*)&w1t[(size_t)ncol * 32 + ko1];
                f32x4 acc = {0.f, 0.f, 0.f, 0.f};
                acc = __builtin_amdgcn_mfma_f32_16x16x32_bf16(eafr, bfr, acc, 0, 0, 0);
                float b = fc_b1[ncol];
#pragma unroll
                for (int r = 0; r < 4; ++r)
                    h_lds[r0 + r][ncol] = f2bf(fmaxf(acc[r] + b, 0.f));
            }
        }
    }
    __syncthreads();

    // ---- B fragments: wave owns TWO 16-edge groups (AI x2 on the W2 stream) ----
    const int e16 = lane & 15;
    const int hi  = lane >> 4;
    const int elA = wave * 16 + e16;
    const int elB = 64 + elA;
    const int ko  = hi * 8;
    bf16x8 hfA[4], hfB[4];
#pragma unroll
    for (int kk = 0; kk < 4; ++kk) {
        hfA[kk] = *(const bf16x8*)&h_lds[elA][kk * 32 + ko];
        hfB[kk] = *(const bf16x8*)&h_lds[elB][kk * 32 + ko];
    }
    __syncthreads();   // h dead -> coefb overlay may be written

    // ---- Phase 1b: gather node_attr[dst], build bf16 coef tables (overlay) ----
    u16* coefb = uregion;
    {
        float sh0 = SHs[ce][0], s1a = SHs[ce][1], s1b = SHs[ce][2], s1c = SHs[ce][3];
        const float* na = node_attr + (size_t)cdst * 80;
        float l1c = A0C * sh0;
#pragma unroll
        for (int q = 0; q < 16; ++q) {
            int u = q * 2 + t2;
            float x = cvalid ? na[u] : 0.f;
            coefb[u * CBS + ce]        = f2bf(l1c * x);
            coefb[(32 + u) * CBS + ce] = f2bf(x);
        }
#pragma unroll
        for (int q = 0; q < 8; ++q) {
            int u = q * 2 + t2;
            float xa = cvalid ? na[32 + u * 3 + 0] : 0.f;
            float xb = cvalid ? na[32 + u * 3 + 1] : 0.f;
            float xc = cvalid ? na[32 + u * 3 + 2] : 0.f;
            coefb[(64 + u * 3 + 0) * CBS + ce] = f2bf(xa);
            coefb[(64 + u * 3 + 1) * CBS + ce] = f2bf(xb);
            coefb[(64 + u * 3 + 2) * CBS + ce] = f2bf(xc);
            coefb[(112 + u) * CBS + ce] = f2bf(A0IS3 * (xa * s1a + xb * s1b + xc * s1c));
        }
    }
    __syncthreads();

    // Per-group accumulators: lane owns edges elA/elB, n-rows 4*hi+r of each tile.
    float o0aA[4] = {}, o0bA[4] = {}, q2A[4] = {}, q3A[3][4] = {};
    float o0aB[4] = {}, o0bB[4] = {}, q2B[4] = {}, q3B[3][4] = {};

    auto epi = [&](const f32x4& acc, const f32x4& bv, int gnt, int el,
                   float (&o0a)[4], float (&o0b)[4], float (&q2)[4], float (&q3)[3][4]) {
        float av[4];
#pragma unroll
        for (int r = 0; r < 4; ++r) av[r] = acc[r] + bv[r];
        if (gnt < 64) {
            float c = bf2f(coefb[(gnt >> 1) * CBS + el]);
            if (gnt & 1) {
#pragma unroll
                for (int r = 0; r < 4; ++r) o0b[r] += c * av[r];
            } else {
#pragma unroll
                for (int r = 0; r < 4; ++r) o0a[r] += c * av[r];
            }
        } else if (gnt < 96) {
            float c = bf2f(coefb[(32 + gnt - 64) * CBS + el]);
#pragma unroll
            for (int r = 0; r < 4; ++r) q2[r] += c * av[r];
        } else if (gnt < 112) {
            int u = gnt - 96;
            float c0 = bf2f(coefb[(64 + u * 3 + 0) * CBS + el]);
            float c1 = bf2f(coefb[(64 + u * 3 + 1) * CBS + el]);
            float c2 = bf2f(coefb[(64 + u * 3 + 2) * CBS + el]);
#pragma unroll
            for (int r = 0; r < 4; ++r) {
                float a = av[r];
                q3[0][r] += c0 * a;
                q3[1][r] += c1 * a;
                q3[2][r] += c2 * a;
            }
        } else {
            int idx = gnt - 112;
            float c = bf2f(coefb[(112 + (idx >> 1)) * CBS + el]);
            if (idx & 1) {
#pragma unroll
                for (int r = 0; r < 4; ++r) o0b[r] += c * av[r];
            } else {
#pragma unroll
                for (int r = 0; r < 4; ++r) o0a[r] += c * av[r];
            }
        }
    };

    auto step = [&](const bf16x8 (&afr)[4], const f32x4& bv, int gnt) {
        f32x4 accA = {0.f, 0.f, 0.f, 0.f};
        f32x4 accB = {0.f, 0.f, 0.f, 0.f};
#pragma unroll
        for (int kk = 0; kk < 4; ++kk) {   // one A-load feeds BOTH edge groups
            accA = __builtin_amdgcn_mfma_f32_16x16x32_bf16(afr[kk], hfA[kk], accA, 0, 0, 0);
            accB = __builtin_amdgcn_mfma_f32_16x16x32_bf16(afr[kk], hfB[kk], accB, 0, 0, 0);
        }
        epi(accA, bv, gnt, elA, o0aA, o0bA, q2A, q3A);
        epi(accB, bv, gnt, elB, o0aB, o0bB, q2B, q3B);
    };

    // ---- Phase 2: 144 N-tiles; A = W2 stream from L2, 2-deep reg prefetch ----
    const u16* pt = w2frag + (size_t)lane * 8;   // tile stride 2048 u16
    const float* b2p = fc_b2 + hi * 4;           // + 16 per tile
    bf16x8 aA[4], aB[4];
    f32x4 bvA, bvB;
#pragma unroll
    for (int kk = 0; kk < 4; ++kk) aA[kk] = *(const bf16x8*)(pt + kk * 512);
    bvA = *(const f32x4*)(b2p + 0);
    for (int t = 0; t < 144; t += 2) {
#pragma unroll
        for (int kk = 0; kk < 4; ++kk) aB[kk] = *(const bf16x8*)(pt + 2048 + kk * 512);
        bvB = *(const f32x4*)(b2p + (t + 1) * 16);
        step(aA, bvA, t);
        if (t + 2 < 144) {
#pragma unroll
            for (int kk = 0; kk < 4; ++kk) aA[kk] = *(const bf16x8*)(pt + 4096 + kk * 512);
            bvA = *(const f32x4*)(b2p + (t + 2) * 16);
        }
        step(aB, bvB, t + 1);
        pt += 4096;
    }
    __syncthreads();   // coefb dead -> tp overlay may be written

    // ---- Phase 3a: write per-edge outputs for both groups ----
    float* tp = (float*)uregion;
    {
        auto wout = [&](int el, float (&o0a)[4], float (&o0b)[4],
                        float (&q2)[4], float (&q3)[3][4]) {
            float sh0 = SHs[el][0], s1a = SHs[el][1], s1b = SHs[el][2], s1c = SHs[el][3];
            float g  = A1IS3 * sh0;
            float sa = A1IS3 * s1a, sb = A1IS3 * s1b, sc = A1IS3 * s1c;
#pragma unroll
            for (int r = 0; r < 4; ++r) {
                int v = hi * 4 + r;
                tp[v * TPS + el]        = o0a[r];
                tp[(16 + v) * TPS + el] = o0b[r];
                float qv = q2[r];
                tp[(32 + 3 * v + 0) * TPS + el] = qv * sa + g * q3[0][r];
                tp[(32 + 3 * v + 1) * TPS + el] = qv * sb + g * q3[1][r];
                tp[(32 + 3 * v + 2) * TPS + el] = qv * sc + g * q3[2][r];
            }
        };
        wout(elA, o0aA, o0bA, q2A, q3A);
        wout(elB, o0aB, o0bB, q2B, q3B);
    }
    __syncthreads();

    // ---- Phase 3b: per-run serial sum + one atomic per (run, component) ----
    for (int i = tid; i < E_TILE * 80; i += 256) {
        int e = i & 127, c = i >> 7;
        int len = RLEN[e];
        if (len > 0 && SRCs[e] >= 0) {
            float s = 0.f;
            for (int k = 0; k < len; ++k) s += tp[c * TPS + e + k];
            unsafeAtomicAdd(&out[(size_t)SRCs[e] * 80 + c], s);
        }
    }
}

extern "C" void kernel_launch(void* const* d_in, const int* in_sizes, int n_in,
                              void* d_out, int out_size, void* d_ws, size_t ws_size,
                              hipStream_t stream) {
    const float* node_attr  = (const float*)d_in[0];
    const int*   edge_index = (const int*)d_in[1];
    const float* edge_attr  = (const float*)d_in[2];
    const float* edge_sh    = (const float*)d_in[3];
    const float* fc_w1      = (const float*)d_in[4];
    const float* fc_b1      = (const float*)d_in[5];
    const float* fc_w2      = (const float*)d_in[6];
    const float* fc_b2      = (const float*)d_in[7];
    int N = in_sizes[0] / 80;
    int E = in_sizes[1] / 2;
    float* out = (float*)d_out;

    int* cnt  = (int*)d_ws;
    int* cur  = cnt + N;
    int* perm = cur + N;
    u16* w2frag = (u16*)(perm + E);              // 294912 u16
    u16* w1t    = w2frag + (size_t)NTILES * 4 * 64 * 8;

    hipMemsetAsync(out, 0, (size_t)N * 80 * 4, stream);
    hipMemsetAsync(cnt, 0, (size_t)N * 4, stream);

    int prep_total = NTILES * 4 * 64 * 8 + 128 * 32;
    prep_w<<<(prep_total + 255) / 256, 256, 0, stream>>>(fc_w2, fc_w1, w2frag, w1t);
    count_k<<<(E + 255) / 256, 256, 0, stream>>>(edge_index, E, cnt);
    scan_k<<<1, 1024, 0, stream>>>(cnt, cur, N);
    scatter_k<<<(E + 255) / 256, 256, 0, stream>>>(edge_index, E, cur, perm);
    tpcl_main<<<(E + E_TILE - 1) / E_TILE, 256, 0, stream>>>(
        node_attr, edge_index, edge_attr, edge_sh, w1t, fc_b1, fc_b2, w2frag, perm, out, N, E);
    finalize_k<<<(N * 80 + 255) / 256, 256, 0, stream>>>(out, cnt, N * 80);
}